// Round 5
// baseline (1004.843 us; speedup 1.0000x reference)
//
#include <hip/hip_runtime.h>

#define EPSV 1e-5f

typedef unsigned short u16;
typedef __attribute__((ext_vector_type(8))) _Float16 half8;
typedef __attribute__((ext_vector_type(4))) float floatx4;

__device__ __forceinline__ float h2f(u16 h) {
    return (float)__builtin_bit_cast(_Float16, h);
}
__device__ __forceinline__ u16 f2h(float f) {
    _Float16 h = (_Float16)f;
    return __builtin_bit_cast(u16, h);
}

// ---------------------------------------------------------------------------
// NT fp16 MFMA GEMM: D[i][j] = sum_k A[i][k] * B[j][k]
// A: [I][ldA] fp16 (K contiguous), B: [J][ldB] fp16 (K contiguous)
// Tile 128x128, BK=32, 256 threads (4 waves, each a 64x64 quadrant, 16 MFMAs).
// Staging via global_load_lds width=16 (m97 structure).
// MODE: 0 = plain (fp32 out), 1 = BN+ReLU per col j, 2 = BN+ReLU per row i,
//       3 = add fp16 tensor `addf` (same layout/strides as C)
// ---------------------------------------------------------------------------
template <int MODE, typename OUTT>
__global__ __launch_bounds__(256)
void gemm_nt(const u16* __restrict__ A, const u16* __restrict__ B,
             OUTT* __restrict__ C_,
             const float* __restrict__ inv_, const float* __restrict__ beta_,
             const u16* __restrict__ addf,
             int K, int ldA, int ldB, int ldC,
             long strideA, long strideB, long strideC)
{
    __shared__ u16 As[128 * 32];
    __shared__ u16 Bs[128 * 32];

    const int tid = threadIdx.x;
    const int w = tid >> 6;        // wave 0..3
    const int l = tid & 63;        // lane
    const int j0 = blockIdx.x * 128;
    const int i0 = blockIdx.y * 128;

    const u16* Ab = A + (long)blockIdx.z * strideA;
    const u16* Bb = B + (long)blockIdx.z * strideB;

    // staging: per issue, wave w covers 16 rows (lane/4), granule (lane&3)*8 elems
    const int srow = w * 16 + (l >> 2);   // 0..63 (+64 for second issue)
    const int skel = (l & 3) * 8;         // k element offset

    // compute mapping: wave quadrant
    const int i_base = (w >> 1) * 64;
    const int j_base = (w & 1) * 64;
    const int lm = l & 15;
    const int kq = l >> 4;                // 0..3

    floatx4 acc[4][4];
    #pragma unroll
    for (int a = 0; a < 4; ++a)
        #pragma unroll
        for (int b = 0; b < 4; ++b) acc[a][b] = (floatx4)(0.0f);

    for (int k0 = 0; k0 < K; k0 += 32) {
        const u16* ga0 = Ab + (long)(i0 + srow) * ldA + k0 + skel;
        const u16* ga1 = Ab + (long)(i0 + 64 + srow) * ldA + k0 + skel;
        const u16* gb0 = Bb + (long)(j0 + srow) * ldB + k0 + skel;
        const u16* gb1 = Bb + (long)(j0 + 64 + srow) * ldB + k0 + skel;
        char* la0 = (char*)As + w * 1024;
        char* la1 = (char*)As + 4096 + w * 1024;
        char* lb0 = (char*)Bs + w * 1024;
        char* lb1 = (char*)Bs + 4096 + w * 1024;
        __builtin_amdgcn_global_load_lds(
            (const __attribute__((address_space(1))) unsigned int*)(const void*)ga0,
            (__attribute__((address_space(3))) unsigned int*)(void*)la0, 16, 0, 0);
        __builtin_amdgcn_global_load_lds(
            (const __attribute__((address_space(1))) unsigned int*)(const void*)ga1,
            (__attribute__((address_space(3))) unsigned int*)(void*)la1, 16, 0, 0);
        __builtin_amdgcn_global_load_lds(
            (const __attribute__((address_space(1))) unsigned int*)(const void*)gb0,
            (__attribute__((address_space(3))) unsigned int*)(void*)lb0, 16, 0, 0);
        __builtin_amdgcn_global_load_lds(
            (const __attribute__((address_space(1))) unsigned int*)(const void*)gb1,
            (__attribute__((address_space(3))) unsigned int*)(void*)lb1, 16, 0, 0);
        __syncthreads();

        half8 af[4], bf[4];
        #pragma unroll
        for (int t = 0; t < 4; ++t) {
            af[t] = *(const half8*)&As[(i_base + t * 16 + lm) * 32 + kq * 8];
            bf[t] = *(const half8*)&Bs[(j_base + t * 16 + lm) * 32 + kq * 8];
        }
        #pragma unroll
        for (int ti = 0; ti < 4; ++ti)
            #pragma unroll
            for (int tj = 0; tj < 4; ++tj)
                acc[ti][tj] = __builtin_amdgcn_mfma_f32_16x16x32_f16(
                    af[ti], bf[tj], acc[ti][tj], 0, 0, 0);
        __syncthreads();
    }

    OUTT* Cb = C_ + (long)blockIdx.z * strideC;
    const u16* addb = (MODE == 3) ? addf + (long)blockIdx.z * strideC : nullptr;
    #pragma unroll
    for (int ti = 0; ti < 4; ++ti) {
        #pragma unroll
        for (int tj = 0; tj < 4; ++tj) {
            const int jj = j0 + j_base + tj * 16 + lm;
            float cinv = 0.f, cbeta = 0.f;
            if (MODE == 1) { cinv = inv_[jj]; cbeta = beta_[jj]; }
            #pragma unroll
            for (int r = 0; r < 4; ++r) {
                const int ii = i0 + i_base + ti * 16 + kq * 4 + r;
                float val = acc[ti][tj][r];
                if (MODE == 1) val = fmaxf(val * cinv + cbeta, 0.0f);
                if (MODE == 2) {
                    float iv = inv_[ii], bt = beta_[ii];
                    val = fmaxf(val * iv + bt, 0.0f);
                }
                if (MODE == 3) val += h2f(addb[(long)ii * ldC + jj]);
                if (sizeof(OUTT) == 4) {
                    ((float*)Cb)[(long)ii * ldC + jj] = val;
                } else {
                    ((u16*)Cb)[(long)ii * ldC + jj] = f2h(val);
                }
            }
        }
    }
}

// ---------------------------------------------------------------------------
// weight fp32 -> fp16 + precompute BN inv/beta
// ---------------------------------------------------------------------------
__global__ __launch_bounds__(256)
void conv_weight(const float* __restrict__ W, const float* __restrict__ g,
                 const float* __restrict__ b, const float* __restrict__ m,
                 const float* __restrict__ v,
                 u16* __restrict__ Wb, float* __restrict__ inv_,
                 float* __restrict__ beta_, int cout, long n)
{
    for (long idx = (long)blockIdx.x * 256 + threadIdx.x; idx < n;
         idx += (long)gridDim.x * 256)
        Wb[idx] = f2h(W[idx]);
    int c = blockIdx.x * 256 + threadIdx.x;
    if (c < cout) {
        float iv = g[c] * rsqrtf(v[c] + EPSV);
        inv_[c] = iv;
        beta_[c] = b[c] - m[c] * iv;
    }
}

// ---------------------------------------------------------------------------
// feature [C][N] fp32 -> featT [N][C] fp16 (32x32 tiled transpose), per batch z
// ---------------------------------------------------------------------------
__global__ __launch_bounds__(256)
void transpose_conv(const float* __restrict__ in, u16* __restrict__ out,
                    int C, int N)
{
    __shared__ float t[32][33];
    const int n0 = blockIdx.x * 32, c0 = blockIdx.y * 32;
    const float* inb = in + (long)blockIdx.z * C * N;
    u16* outb = out + (long)blockIdx.z * C * N;
    const int tx = threadIdx.x & 31, ty = threadIdx.x >> 5;  // 32 x 8
    #pragma unroll
    for (int rr = 0; rr < 32; rr += 8)
        t[ty + rr][tx] = inb[(long)(c0 + ty + rr) * N + n0 + tx];
    __syncthreads();
    #pragma unroll
    for (int rr = 0; rr < 32; rr += 8)
        outb[(long)(n0 + ty + rr) * C + c0 + tx] = f2h(t[tx][ty + rr]);
}

// ---------------------------------------------------------------------------
// Row softmax on S fp32 [B][4096][4096]; writes fp16 result in-place over the
// first half of each row's own storage (row pitch stays 16384 B -> ld 8192 u16)
// blockIdx.x = row, blockIdx.y = batch
// ---------------------------------------------------------------------------
__global__ __launch_bounds__(256)
void softmax_f16(float* __restrict__ S)
{
    __shared__ float buf[4096];
    __shared__ float red[256];
    float* p = S + (long)blockIdx.y * 4096 * 4096 + (long)blockIdx.x * 4096;
    u16* o = (u16*)p;
    const int tid = threadIdx.x;

    float lmax = -3.4e38f;
    for (int i = tid; i < 4096; i += 256) {
        float x = p[i];
        buf[i] = x;
        lmax = fmaxf(lmax, x);
    }
    red[tid] = lmax;
    __syncthreads();
    for (int s = 128; s > 0; s >>= 1) {
        if (tid < s) red[tid] = fmaxf(red[tid], red[tid + s]);
        __syncthreads();
    }
    const float mx = red[0];
    __syncthreads();

    float lsum = 0.0f;
    for (int i = tid; i < 4096; i += 256) {
        float e = __expf(buf[i] - mx);
        buf[i] = e;
        lsum += e;
    }
    red[tid] = lsum;
    __syncthreads();
    for (int s = 128; s > 0; s >>= 1) {
        if (tid < s) red[tid] += red[tid + s];
        __syncthreads();
    }
    const float invs = 1.0f / red[0];
    __syncthreads();

    for (int i = tid; i < 4096; i += 256) o[i] = f2h(buf[i] * invs);
}

// ---------------------------------------------------------------------------
extern "C" void kernel_launch(void* const* d_in, const int* in_sizes, int n_in,
                              void* d_out, int out_size, void* d_ws, size_t ws_size,
                              hipStream_t stream)
{
    (void)in_sizes; (void)n_in; (void)out_size; (void)ws_size;
    constexpr int B = 4, C = 2048, R = 512, N = 4096;
    constexpr long NR = (long)N * R;   // 2,097,152
    constexpr long NC = (long)N * C;   // 8,388,608
    constexpr long NN = (long)N * N;   // 16,777,216

    const float* feature = (const float*)d_in[0];
    const float* W_[5]  = {(const float*)d_in[1],  (const float*)d_in[6],
                           (const float*)d_in[11], (const float*)d_in[16],
                           (const float*)d_in[21]};
    const float* G_[5]  = {(const float*)d_in[2],  (const float*)d_in[7],
                           (const float*)d_in[12], (const float*)d_in[17],
                           (const float*)d_in[22]};
    const float* Bb_[5] = {(const float*)d_in[3],  (const float*)d_in[8],
                           (const float*)d_in[13], (const float*)d_in[18],
                           (const float*)d_in[23]};
    const float* M_[5]  = {(const float*)d_in[4],  (const float*)d_in[9],
                           (const float*)d_in[14], (const float*)d_in[19],
                           (const float*)d_in[24]};
    const float* V_[5]  = {(const float*)d_in[5],  (const float*)d_in[10],
                           (const float*)d_in[15], (const float*)d_in[20],
                           (const float*)d_in[25]};
    const int cout_[5] = {R, R, R, R, C};
    const int cin_[5]  = {C, R, R, R, R};

    // ---- workspace layout (bytes), ws = 512 MiB ----
    char* base = (char*)d_ws;
    size_t off = 0;
    // region0: S fp32 [B][N][N] = 268 MB. featT fp16 [B][N][C] (67 MB)
    // aliases its head -- featT is dead before the first S write (logits).
    float* S     = (float*)base;
    u16*   featT = (u16*)base;
    off += (size_t)B * NN * 4;                         // 268,435,456
    u16* fT = (u16*)(base + off);                      off += (size_t)B * NR * 2;
    u16* qT = (u16*)(base + off);                      off += (size_t)B * NR * 2;
    u16* kT = (u16*)(base + off);                      off += (size_t)B * NR * 2;
    u16* vC = (u16*)(base + off);                      off += (size_t)B * NR * 2;
    u16* gT = (u16*)(base + off);                      off += (size_t)B * NR * 2;
    u16* Wb_[5]; float* inv_[5]; float* beta_[5];
    for (int i = 0; i < 5; ++i) {
        Wb_[i] = (u16*)(base + off);  off += (size_t)cout_[i] * cin_[i] * 2;
        off = (off + 255) & ~(size_t)255;
    }
    for (int i = 0; i < 5; ++i) {
        inv_[i]  = (float*)(base + off);  off += 8192;
        beta_[i] = (float*)(base + off);  off += 8192;
    }

    float* out = (float*)d_out;
    const dim3 blk(256);

    // ---- weight conversion + BN param precompute ----
    for (int i = 0; i < 5; ++i)
        conv_weight<<<512, blk, 0, stream>>>(W_[i], G_[i], Bb_[i], M_[i], V_[i],
                                             Wb_[i], inv_[i], beta_[i],
                                             cout_[i], (long)cout_[i] * cin_[i]);

    // ---- feature transpose+convert: [B][C][N] f32 -> [B][N][C] fp16 ----
    transpose_conv<<<dim3(N / 32, C / 32, B), blk, 0, stream>>>(feature, featT, C, N);

    // ---- f = CBR(feature, r): out fT [B][N][R] fp16 ----
    gemm_nt<1, u16><<<dim3(R / 128, N / 128, B), blk, 0, stream>>>(
        featT, Wb_[0], fT, inv_[0], beta_[0], nullptr,
        C, C, C, R, NC, 0, NR);

    // ---- q,k = CBR(f): [B][N][R] fp16 ----
    gemm_nt<1, u16><<<dim3(R / 128, N / 128, B), blk, 0, stream>>>(
        fT, Wb_[1], qT, inv_[1], beta_[1], nullptr,
        R, R, R, R, NR, 0, NR);
    gemm_nt<1, u16><<<dim3(R / 128, N / 128, B), blk, 0, stream>>>(
        fT, Wb_[2], kT, inv_[2], beta_[2], nullptr,
        R, R, R, R, NR, 0, NR);
    // ---- v = CBR(f), channel-major: vC [B][R][N] fp16 ----
    gemm_nt<2, u16><<<dim3(N / 128, R / 128, B), blk, 0, stream>>>(
        Wb_[3], fT, vC, inv_[3], beta_[3], nullptr,
        R, R, R, N, 0, NR, NR);

    // ---- logits, all batches: S[b][i][m] = sum_r q[i][r]*k[m][r] (fp32) ----
    gemm_nt<0, float><<<dim3(N / 128, N / 128, B), blk, 0, stream>>>(
        qT, kT, S, nullptr, nullptr, nullptr,
        R, R, R, N, NR, NR, NN);

    // ---- softmax rows, all batches; fp16 P in place (row pitch 8192 u16) ----
    softmax_f16<<<dim3(N, B), blk, 0, stream>>>(S);

    // ---- upd, all batches: gT[b][n][c] = fT[b][n][c] + sum_m P[n][m]*vC[c][m]
    gemm_nt<3, u16><<<dim3(R / 128, N / 128, B), blk, 0, stream>>>(
        (const u16*)S, vC, gT, nullptr, nullptr, fT,
        N, 2 * N, N, R, 2 * NN, NR, NR);

    // ---- out = CBR(f + upd, u): [B][C][N] fp32 ----
    gemm_nt<2, float><<<dim3(N / 128, C / 128, B), blk, 0, stream>>>(
        Wb_[4], gT, out, inv_[4], beta_[4], nullptr,
        R, R, R, N, 0, NR, NC);
}

// Round 6
// 830.631 us; speedup vs baseline: 1.2097x; 1.2097x over previous
//
#include <hip/hip_runtime.h>

#define EPSV 1e-5f

typedef unsigned short u16;
typedef __attribute__((ext_vector_type(8))) _Float16 half8;
typedef __attribute__((ext_vector_type(4))) float floatx4;

__device__ __forceinline__ float h2f(u16 h) {
    return (float)__builtin_bit_cast(_Float16, h);
}
__device__ __forceinline__ u16 f2h(float f) {
    _Float16 h = (_Float16)f;
    return __builtin_bit_cast(u16, h);
}

// ---------------------------------------------------------------------------
// NT fp16 MFMA GEMM: D[i][j] = sum_k A[i][k] * B[j][k]
// A: [I][ldA] fp16 (K contiguous), B: [J][ldB] fp16 (K contiguous)
// Tile 128x128, BK=32, 256 threads (4 waves, each a 64x64 quadrant, 16 MFMAs).
// Staging via global_load_lds width=16 (m97 structure).
// MODE: 0 = plain (fp32 out), 1 = BN+ReLU per col j, 2 = BN+ReLU per row i,
//       3 = add fp16 tensor `addf` (same layout/strides as C)
// ---------------------------------------------------------------------------
template <int MODE, typename OUTT>
__global__ __launch_bounds__(256)
void gemm_nt(const u16* __restrict__ A, const u16* __restrict__ B,
             OUTT* __restrict__ C_,
             const float* __restrict__ inv_, const float* __restrict__ beta_,
             const u16* __restrict__ addf,
             int K, int ldA, int ldB, int ldC,
             long strideA, long strideB, long strideC)
{
    __shared__ u16 As[128 * 32];
    __shared__ u16 Bs[128 * 32];

    const int tid = threadIdx.x;
    const int w = tid >> 6;        // wave 0..3
    const int l = tid & 63;        // lane
    const int j0 = blockIdx.x * 128;
    const int i0 = blockIdx.y * 128;

    const u16* Ab = A + (long)blockIdx.z * strideA;
    const u16* Bb = B + (long)blockIdx.z * strideB;

    // staging: per issue, wave w covers 16 rows (lane/4), granule (lane&3)*8 elems
    const int srow = w * 16 + (l >> 2);   // 0..63 (+64 for second issue)
    const int skel = (l & 3) * 8;         // k element offset

    // compute mapping: wave quadrant
    const int i_base = (w >> 1) * 64;
    const int j_base = (w & 1) * 64;
    const int lm = l & 15;
    const int kq = l >> 4;                // 0..3

    floatx4 acc[4][4];
    #pragma unroll
    for (int a = 0; a < 4; ++a)
        #pragma unroll
        for (int b = 0; b < 4; ++b) acc[a][b] = (floatx4)(0.0f);

    for (int k0 = 0; k0 < K; k0 += 32) {
        const u16* ga0 = Ab + (long)(i0 + srow) * ldA + k0 + skel;
        const u16* ga1 = Ab + (long)(i0 + 64 + srow) * ldA + k0 + skel;
        const u16* gb0 = Bb + (long)(j0 + srow) * ldB + k0 + skel;
        const u16* gb1 = Bb + (long)(j0 + 64 + srow) * ldB + k0 + skel;
        char* la0 = (char*)As + w * 1024;
        char* la1 = (char*)As + 4096 + w * 1024;
        char* lb0 = (char*)Bs + w * 1024;
        char* lb1 = (char*)Bs + 4096 + w * 1024;
        __builtin_amdgcn_global_load_lds(
            (const __attribute__((address_space(1))) unsigned int*)(const void*)ga0,
            (__attribute__((address_space(3))) unsigned int*)(void*)la0, 16, 0, 0);
        __builtin_amdgcn_global_load_lds(
            (const __attribute__((address_space(1))) unsigned int*)(const void*)ga1,
            (__attribute__((address_space(3))) unsigned int*)(void*)la1, 16, 0, 0);
        __builtin_amdgcn_global_load_lds(
            (const __attribute__((address_space(1))) unsigned int*)(const void*)gb0,
            (__attribute__((address_space(3))) unsigned int*)(void*)lb0, 16, 0, 0);
        __builtin_amdgcn_global_load_lds(
            (const __attribute__((address_space(1))) unsigned int*)(const void*)gb1,
            (__attribute__((address_space(3))) unsigned int*)(void*)lb1, 16, 0, 0);
        __syncthreads();

        half8 af[4], bf[4];
        #pragma unroll
        for (int t = 0; t < 4; ++t) {
            af[t] = *(const half8*)&As[(i_base + t * 16 + lm) * 32 + kq * 8];
            bf[t] = *(const half8*)&Bs[(j_base + t * 16 + lm) * 32 + kq * 8];
        }
        #pragma unroll
        for (int ti = 0; ti < 4; ++ti)
            #pragma unroll
            for (int tj = 0; tj < 4; ++tj)
                acc[ti][tj] = __builtin_amdgcn_mfma_f32_16x16x32_f16(
                    af[ti], bf[tj], acc[ti][tj], 0, 0, 0);
        __syncthreads();
    }

    OUTT* Cb = C_ + (long)blockIdx.z * strideC;
    const u16* addb = (MODE == 3) ? addf + (long)blockIdx.z * strideC : nullptr;
    #pragma unroll
    for (int ti = 0; ti < 4; ++ti) {
        #pragma unroll
        for (int tj = 0; tj < 4; ++tj) {
            const int jj = j0 + j_base + tj * 16 + lm;
            float cinv = 0.f, cbeta = 0.f;
            if (MODE == 1) { cinv = inv_[jj]; cbeta = beta_[jj]; }
            #pragma unroll
            for (int r = 0; r < 4; ++r) {
                const int ii = i0 + i_base + ti * 16 + kq * 4 + r;
                float val = acc[ti][tj][r];
                if (MODE == 1) val = fmaxf(val * cinv + cbeta, 0.0f);
                if (MODE == 2) {
                    float iv = inv_[ii], bt = beta_[ii];
                    val = fmaxf(val * iv + bt, 0.0f);
                }
                if (MODE == 3) val += h2f(addb[(long)ii * ldC + jj]);
                if (sizeof(OUTT) == 4) {
                    ((float*)Cb)[(long)ii * ldC + jj] = val;
                } else {
                    ((u16*)Cb)[(long)ii * ldC + jj] = f2h(val);
                }
            }
        }
    }
}

// ---------------------------------------------------------------------------
// weight fp32 -> fp16 + precompute BN inv/beta
// ---------------------------------------------------------------------------
__global__ __launch_bounds__(256)
void conv_weight(const float* __restrict__ W, const float* __restrict__ g,
                 const float* __restrict__ b, const float* __restrict__ m,
                 const float* __restrict__ v,
                 u16* __restrict__ Wb, float* __restrict__ inv_,
                 float* __restrict__ beta_, int cout, long n)
{
    for (long idx = (long)blockIdx.x * 256 + threadIdx.x; idx < n;
         idx += (long)gridDim.x * 256)
        Wb[idx] = f2h(W[idx]);
    int c = blockIdx.x * 256 + threadIdx.x;
    if (c < cout) {
        float iv = g[c] * rsqrtf(v[c] + EPSV);
        inv_[c] = iv;
        beta_[c] = b[c] - m[c] * iv;
    }
}

// ---------------------------------------------------------------------------
// feature [C][N] fp32 -> featT [N][C] fp16 (32x32 tiled transpose), per batch z
// ---------------------------------------------------------------------------
__global__ __launch_bounds__(256)
void transpose_conv(const float* __restrict__ in, u16* __restrict__ out,
                    int C, int N)
{
    __shared__ float t[32][33];
    const int n0 = blockIdx.x * 32, c0 = blockIdx.y * 32;
    const float* inb = in + (long)blockIdx.z * C * N;
    u16* outb = out + (long)blockIdx.z * C * N;
    const int tx = threadIdx.x & 31, ty = threadIdx.x >> 5;  // 32 x 8
    #pragma unroll
    for (int rr = 0; rr < 32; rr += 8)
        t[ty + rr][tx] = inb[(long)(c0 + ty + rr) * N + n0 + tx];
    __syncthreads();
    #pragma unroll
    for (int rr = 0; rr < 32; rr += 8)
        outb[(long)(n0 + ty + rr) * C + c0 + tx] = f2h(t[tx][ty + rr]);
}

// ---------------------------------------------------------------------------
// Row softmax: reads S fp32 [B][4096][4096], writes COMPACT P fp16
// [B][4096][4096] (134 MB -- L3-resident for the following upd GEMM).
// blockIdx.x = row, blockIdx.y = batch
// ---------------------------------------------------------------------------
__global__ __launch_bounds__(256)
void softmax_f16(const float* __restrict__ S, u16* __restrict__ P)
{
    __shared__ float buf[4096];
    __shared__ float red[256];
    const float* p = S + (long)blockIdx.y * 4096 * 4096 + (long)blockIdx.x * 4096;
    u16* o = P + (long)blockIdx.y * 4096 * 4096 + (long)blockIdx.x * 4096;
    const int tid = threadIdx.x;

    float lmax = -3.4e38f;
    for (int i = tid; i < 4096; i += 256) {
        float x = p[i];
        buf[i] = x;
        lmax = fmaxf(lmax, x);
    }
    red[tid] = lmax;
    __syncthreads();
    for (int s = 128; s > 0; s >>= 1) {
        if (tid < s) red[tid] = fmaxf(red[tid], red[tid + s]);
        __syncthreads();
    }
    const float mx = red[0];
    __syncthreads();

    float lsum = 0.0f;
    for (int i = tid; i < 4096; i += 256) {
        float e = __expf(buf[i] - mx);
        buf[i] = e;
        lsum += e;
    }
    red[tid] = lsum;
    __syncthreads();
    for (int s = 128; s > 0; s >>= 1) {
        if (tid < s) red[tid] += red[tid + s];
        __syncthreads();
    }
    const float invs = 1.0f / red[0];
    __syncthreads();

    for (int i = tid; i < 4096; i += 256) o[i] = f2h(buf[i] * invs);
}

// ---------------------------------------------------------------------------
extern "C" void kernel_launch(void* const* d_in, const int* in_sizes, int n_in,
                              void* d_out, int out_size, void* d_ws, size_t ws_size,
                              hipStream_t stream)
{
    (void)in_sizes; (void)n_in; (void)out_size; (void)ws_size;
    constexpr int B = 4, C = 2048, R = 512, N = 4096;
    constexpr long NR = (long)N * R;   // 2,097,152
    constexpr long NC = (long)N * C;   // 8,388,608
    constexpr long NN = (long)N * N;   // 16,777,216

    const float* feature = (const float*)d_in[0];
    const float* W_[5]  = {(const float*)d_in[1],  (const float*)d_in[6],
                           (const float*)d_in[11], (const float*)d_in[16],
                           (const float*)d_in[21]};
    const float* G_[5]  = {(const float*)d_in[2],  (const float*)d_in[7],
                           (const float*)d_in[12], (const float*)d_in[17],
                           (const float*)d_in[22]};
    const float* Bb_[5] = {(const float*)d_in[3],  (const float*)d_in[8],
                           (const float*)d_in[13], (const float*)d_in[18],
                           (const float*)d_in[23]};
    const float* M_[5]  = {(const float*)d_in[4],  (const float*)d_in[9],
                           (const float*)d_in[14], (const float*)d_in[19],
                           (const float*)d_in[24]};
    const float* V_[5]  = {(const float*)d_in[5],  (const float*)d_in[10],
                           (const float*)d_in[15], (const float*)d_in[20],
                           (const float*)d_in[25]};
    const int cout_[5] = {R, R, R, R, C};
    const int cin_[5]  = {C, R, R, R, R};

    // ---- workspace layout (bytes), ws = 512 MiB ----
    // S 268MB + acts 84MB + Pc 134MB + weights 5.8MB + params 0.1MB = 492MB
    char* base = (char*)d_ws;
    size_t off = 0;
    // region0: S fp32 [B][N][N]. featT fp16 [B][N][C] (67 MB) aliases its
    // head -- featT is dead before the first S write (logits).
    float* S     = (float*)base;
    u16*   featT = (u16*)base;
    off += (size_t)B * NN * 4;                         // 268,435,456
    u16* fT = (u16*)(base + off);                      off += (size_t)B * NR * 2;
    u16* qT = (u16*)(base + off);                      off += (size_t)B * NR * 2;
    u16* kT = (u16*)(base + off);                      off += (size_t)B * NR * 2;
    u16* vC = (u16*)(base + off);                      off += (size_t)B * NR * 2;
    u16* gT = (u16*)(base + off);                      off += (size_t)B * NR * 2;
    u16* Pc = (u16*)(base + off);                      off += (size_t)B * NN * 2;
    u16* Wb_[5]; float* inv_[5]; float* beta_[5];
    for (int i = 0; i < 5; ++i) {
        Wb_[i] = (u16*)(base + off);  off += (size_t)cout_[i] * cin_[i] * 2;
        off = (off + 255) & ~(size_t)255;
    }
    for (int i = 0; i < 5; ++i) {
        inv_[i]  = (float*)(base + off);  off += 8192;
        beta_[i] = (float*)(base + off);  off += 8192;
    }

    float* out = (float*)d_out;
    const dim3 blk(256);

    // ---- weight conversion + BN param precompute ----
    for (int i = 0; i < 5; ++i)
        conv_weight<<<512, blk, 0, stream>>>(W_[i], G_[i], Bb_[i], M_[i], V_[i],
                                             Wb_[i], inv_[i], beta_[i],
                                             cout_[i], (long)cout_[i] * cin_[i]);

    // ---- feature transpose+convert: [B][C][N] f32 -> [B][N][C] fp16 ----
    transpose_conv<<<dim3(N / 32, C / 32, B), blk, 0, stream>>>(feature, featT, C, N);

    // ---- f = CBR(feature, r): out fT [B][N][R] fp16 ----
    gemm_nt<1, u16><<<dim3(R / 128, N / 128, B), blk, 0, stream>>>(
        featT, Wb_[0], fT, inv_[0], beta_[0], nullptr,
        C, C, C, R, NC, 0, NR);

    // ---- q,k = CBR(f): [B][N][R] fp16 ----
    gemm_nt<1, u16><<<dim3(R / 128, N / 128, B), blk, 0, stream>>>(
        fT, Wb_[1], qT, inv_[1], beta_[1], nullptr,
        R, R, R, R, NR, 0, NR);
    gemm_nt<1, u16><<<dim3(R / 128, N / 128, B), blk, 0, stream>>>(
        fT, Wb_[2], kT, inv_[2], beta_[2], nullptr,
        R, R, R, R, NR, 0, NR);
    // ---- v = CBR(f), channel-major: vC [B][R][N] fp16 ----
    gemm_nt<2, u16><<<dim3(N / 128, R / 128, B), blk, 0, stream>>>(
        Wb_[3], fT, vC, inv_[3], beta_[3], nullptr,
        R, R, R, N, 0, NR, NR);

    // ---- logits, all batches: S[b][i][m] = sum_r q[i][r]*k[m][r] (fp32) ----
    gemm_nt<0, float><<<dim3(N / 128, N / 128, B), blk, 0, stream>>>(
        qT, kT, S, nullptr, nullptr, nullptr,
        R, R, R, N, NR, NR, NN);

    // ---- softmax rows -> compact fp16 P (L3-resident, 134 MB) ----
    softmax_f16<<<dim3(N, B), blk, 0, stream>>>(S, Pc);

    // ---- upd, all batches: gT[b][n][c] = fT[b][n][c] + sum_m P[n][m]*vC[c][m]
    gemm_nt<3, u16><<<dim3(R / 128, N / 128, B), blk, 0, stream>>>(
        Pc, vC, gT, nullptr, nullptr, fT,
        N, N, N, R, NN, NR, NR);

    // ---- out = CBR(f + upd, u): [B][C][N] fp32 ----
    gemm_nt<2, float><<<dim3(N / 128, C / 128, B), blk, 0, stream>>>(
        Wb_[4], gT, out, inv_[4], beta_[4], nullptr,
        R, R, R, N, 0, NR, NC);
}